// Round 7
// baseline (252.257 us; speedup 1.0000x reference)
//
#include <hip/hip_runtime.h>
#include <hip/hip_bf16.h>

#define NBINS 20
#define TPB 256
#define K 4   // float4 loads per stream per thread per iteration

// Fused single-kernel ECE. Accumulation identical to R6 (at the ~2.9 TB/s
// read-ingress wall): per-thread private LDS columns s[bin][tid], non-atomic
// RMW, bin = ceil((c-0.5)*40)-1 == searchsorted(side='left')-1 (absmax 0.0,
// rounds 1-6). Finalization fused via last-block-done: ordinary partial
// stores + writer __threadfence() (writes back per-XCD L2), device-scope
// counter atomic, reader __threadfence() (invalidates), last block reduces.
__global__ __launch_bounds__(TPB, 8) void ece_fused(
        const float4* __restrict__ confs,
        const float4* __restrict__ accs,
        int n4,                        // n/4
        float* __restrict__ partials,  // [NBINS][nb]
        unsigned int* __restrict__ counter,
        float* __restrict__ out,
        float inv_n, int nb) {
    __shared__ float s[NBINS * TPB];
    __shared__ unsigned int done;
    const int t = threadIdx.x;
#pragma unroll
    for (int k = 0; k < NBINS; ++k) s[k * TPB + t] = 0.0f;
    __syncthreads();

    const int chunk = K * TPB;           // float4s per block per iteration
    const int nIter = n4 / chunk;

    for (int it = blockIdx.x; it < nIter; it += gridDim.x) {
        const int base = it * chunk + t;
        float4 c[K], a[K];
#pragma unroll
        for (int k = 0; k < K; ++k) c[k] = confs[base + k * TPB];
#pragma unroll
        for (int k = 0; k < K; ++k) a[k] = accs[base + k * TPB];

#pragma unroll
        for (int k = 0; k < K; ++k) {
#pragma unroll
            for (int j = 0; j < 4; ++j) {
                float c1 = (j == 0) ? c[k].x : (j == 1) ? c[k].y : (j == 2) ? c[k].z : c[k].w;
                float a1 = (j == 0) ? a[k].x : (j == 1) ? a[k].y : (j == 2) ? a[k].z : a[k].w;
                float ft = __builtin_ceilf((c1 - 0.5f) * 40.0f);
                unsigned int bin = (unsigned int)((int)ft - 1);
                if (bin < (unsigned int)NBINS)
                    s[bin * TPB + t] += c1 - a1;
            }
        }
    }

    // tail (n4 not multiple of chunk) — block 0
    if (blockIdx.x == 0) {
        for (int i = nIter * chunk + t; i < n4; i += TPB) {
            float4 c4 = confs[i];
            float4 a4 = accs[i];
#pragma unroll
            for (int j = 0; j < 4; ++j) {
                float c1 = (j == 0) ? c4.x : (j == 1) ? c4.y : (j == 2) ? c4.z : c4.w;
                float a1 = (j == 0) ? a4.x : (j == 1) ? a4.y : (j == 2) ? a4.z : a4.w;
                float ft = __builtin_ceilf((c1 - 0.5f) * 40.0f);
                unsigned int bin = (unsigned int)((int)ft - 1);
                if (bin < (unsigned int)NBINS)
                    s[bin * TPB + t] += c1 - a1;
            }
        }
    }
    __syncthreads();

    // block reduce, reusing s[]
    float v[NBINS];
#pragma unroll
    for (int b = 0; b < NBINS; ++b) v[b] = s[b * TPB + t];
#pragma unroll
    for (int b = 0; b < NBINS; ++b) {
#pragma unroll
        for (int m = 32; m >= 1; m >>= 1) v[b] += __shfl_xor(v[b], m, 64);
    }
    __syncthreads();
    const int wave = t >> 6, lane = t & 63;
    if (lane == 0) {
#pragma unroll
        for (int b = 0; b < NBINS; ++b) s[b * 4 + wave] = v[b];
    }
    __syncthreads();
    if (t < NBINS) {
        float sum = s[t * 4 + 0] + s[t * 4 + 1] + s[t * 4 + 2] + s[t * 4 + 3];
        partials[t * nb + blockIdx.x] = sum;
    }

    // ---- completion counting (device-scope) ----
    __threadfence();                 // write back partials past per-XCD L2
    __syncthreads();
    if (t == 0) done = atomicAdd(counter, 1u);
    __syncthreads();
    if (done != (unsigned int)(gridDim.x - 1)) return;

    // ---- last block: final reduce ----
    __threadfence();                 // acquire: invalidate stale L1/L2
    float sb[NBINS];
#pragma unroll
    for (int b = 0; b < NBINS; ++b) sb[b] = 0.0f;
    const int nb4 = nb >> 2;         // nb kept a multiple of 4
#pragma unroll
    for (int b = 0; b < NBINS; ++b) {
        const float4* pb = (const float4*)(partials + b * nb);
        for (int k = t; k < nb4; k += TPB) {
            float4 v4 = pb[k];
            sb[b] += (v4.x + v4.y) + (v4.z + v4.w);
        }
    }
#pragma unroll
    for (int b = 0; b < NBINS; ++b) {
#pragma unroll
        for (int m = 32; m >= 1; m >>= 1) sb[b] += __shfl_xor(sb[b], m, 64);
    }
    __syncthreads();
    if (lane == 0) {
#pragma unroll
        for (int b = 0; b < NBINS; ++b) s[b * 4 + wave] = sb[b];
    }
    __syncthreads();
    if (t == 0) {
        float ece = 0.0f;
#pragma unroll
        for (int b = 0; b < NBINS; ++b)
            ece += fabsf(s[b * 4 + 0] + s[b * 4 + 1] + s[b * 4 + 2] + s[b * 4 + 3]);
        out[0] = ece * inv_n;
    }
}

extern "C" void kernel_launch(void* const* d_in, const int* in_sizes, int n_in,
                              void* d_out, int out_size, void* d_ws, size_t ws_size,
                              hipStream_t stream) {
    const float* confs = (const float*)d_in[0];
    const float* accs = (const float*)d_in[1];
    const int n = in_sizes[0];   // 16,777,216
    const int n4 = n / 4;

    // ws layout: [0..15] counter (16 B, keeps partials 16B-aligned), then partials
    unsigned int* counter = (unsigned int*)d_ws;
    float* partials = (float*)((char*)d_ws + 16);

    // grid: 2048 = exactly 8 blocks/CU, all resident in one shot
    int nb = 2048;
    const int chunk = K * TPB;
    int nIter = n4 / chunk;
    if (nb > nIter && nIter >= 4) nb = nIter & ~3;
    int ws_cap = (int)((ws_size - 16) / (NBINS * sizeof(float)));
    ws_cap &= ~3;
    if (nb > ws_cap) nb = ws_cap;
    if (nb < 4) nb = 4;

    hipMemsetAsync(d_ws, 0, 16, stream);  // zero the completion counter

    ece_fused<<<nb, TPB, 0, stream>>>((const float4*)confs, (const float4*)accs,
                                      n4, partials, counter, (float*)d_out,
                                      1.0f / (float)n, nb);
}

// Round 9
// 38.755 us; speedup vs baseline: 6.5090x; 6.5090x over previous
//
#include <hip/hip_runtime.h>
#include <hip/hip_bf16.h>

#define NBINS 20
#define TPB 256
#define K 4   // float4 loads per stream per thread per iteration

typedef float fvec4 __attribute__((ext_vector_type(4)));  // native vector for nontemporal builtin

// Two-kernel structure (R7's threadfence fusion cost 300+ us - reverted).
// Accumulation: non-atomic LDS RMW into s[bin][tid] private columns
// (bank = tid%32, 2-way aliasing = free). bin = ceil((c-0.5)*40)-1 ==
// searchsorted(side='left')-1 (absmax 0.0, rounds 1-7). Invalid samples
// exec-masked. This round: nontemporal (nt) streaming loads via native
// ext_vector_type to test whether the ~3.15 TB/s read wall is the L1/TA
// path or the platform read ceiling.
__global__ __launch_bounds__(TPB, 8) void ece_accum(
        const fvec4* __restrict__ confs,
        const fvec4* __restrict__ accs,
        int n4,                        // n/4
        float* __restrict__ partials,  // [NBINS][nb]
        int nb) {
    __shared__ float s[NBINS * TPB];
    const int t = threadIdx.x;
#pragma unroll
    for (int k = 0; k < NBINS; ++k) s[k * TPB + t] = 0.0f;
    __syncthreads();

    const int chunk = K * TPB;           // float4s per block per iteration
    const int nIter = n4 / chunk;        // 4096 for N=16.7M

    for (int it = blockIdx.x; it < nIter; it += gridDim.x) {
        const int base = it * chunk + t;
        fvec4 c[K], a[K];
#pragma unroll
        for (int k = 0; k < K; ++k) c[k] = __builtin_nontemporal_load(&confs[base + k * TPB]);
#pragma unroll
        for (int k = 0; k < K; ++k) a[k] = __builtin_nontemporal_load(&accs[base + k * TPB]);

#pragma unroll
        for (int k = 0; k < K; ++k) {
#pragma unroll
            for (int j = 0; j < 4; ++j) {
                float c1 = c[k][j];
                float a1 = a[k][j];
                float ft = __builtin_ceilf((c1 - 0.5f) * 40.0f);
                unsigned int bin = (unsigned int)((int)ft - 1);
                if (bin < (unsigned int)NBINS)
                    s[bin * TPB + t] += c1 - a1;
            }
        }
    }

    // tail (n4 not multiple of chunk) — block 0
    if (blockIdx.x == 0) {
        for (int i = nIter * chunk + t; i < n4; i += TPB) {
            fvec4 c4 = confs[i];
            fvec4 a4 = accs[i];
#pragma unroll
            for (int j = 0; j < 4; ++j) {
                float c1 = c4[j];
                float a1 = a4[j];
                float ft = __builtin_ceilf((c1 - 0.5f) * 40.0f);
                unsigned int bin = (unsigned int)((int)ft - 1);
                if (bin < (unsigned int)NBINS)
                    s[bin * TPB + t] += c1 - a1;
            }
        }
    }
    __syncthreads();

    // block reduce, reusing s[]
    float v[NBINS];
#pragma unroll
    for (int b = 0; b < NBINS; ++b) v[b] = s[b * TPB + t];
#pragma unroll
    for (int b = 0; b < NBINS; ++b) {
#pragma unroll
        for (int m = 32; m >= 1; m >>= 1) v[b] += __shfl_xor(v[b], m, 64);
    }
    __syncthreads();
    const int wave = t >> 6, lane = t & 63;
    if (lane == 0) {
#pragma unroll
        for (int b = 0; b < NBINS; ++b) s[b * 4 + wave] = v[b];
    }
    __syncthreads();
    if (t < NBINS) {
        float sum = s[t * 4 + 0] + s[t * 4 + 1] + s[t * 4 + 2] + s[t * 4 + 3];
        partials[t * nb + blockIdx.x] = sum;
    }
}

// One block: reduce nb partials per bin, ece = sum_b |S_b| / N
__global__ __launch_bounds__(512) void ece_final(
        const float* __restrict__ partials,
        float* __restrict__ out,
        float inv_n, int nb) {
    float s[NBINS];
#pragma unroll
    for (int b = 0; b < NBINS; ++b) s[b] = 0.0f;

    const int tid = threadIdx.x;
    const int nb4 = nb >> 2;
#pragma unroll
    for (int b = 0; b < NBINS; ++b) {
        const fvec4* pb = (const fvec4*)(partials + b * nb);
        for (int k = tid; k < nb4; k += blockDim.x) {
            fvec4 v = pb[k];
            s[b] += (v[0] + v[1]) + (v[2] + v[3]);
        }
    }
#pragma unroll
    for (int b = 0; b < NBINS; ++b) {
#pragma unroll
        for (int m = 32; m >= 1; m >>= 1)
            s[b] += __shfl_xor(s[b], m, 64);
    }

    __shared__ float red[NBINS][8];
    const int wave = tid >> 6;
    const int lane = tid & 63;
    if (lane == 0) {
#pragma unroll
        for (int b = 0; b < NBINS; ++b) red[b][wave] = s[b];
    }
    __syncthreads();

    if (tid == 0) {
        float ece = 0.0f;
#pragma unroll
        for (int b = 0; b < NBINS; ++b) {
            float tt = 0.0f;
#pragma unroll
            for (int w = 0; w < 8; ++w) tt += red[b][w];
            ece += fabsf(tt);
        }
        out[0] = ece * inv_n;
    }
}

extern "C" void kernel_launch(void* const* d_in, const int* in_sizes, int n_in,
                              void* d_out, int out_size, void* d_ws, size_t ws_size,
                              hipStream_t stream) {
    const float* confs = (const float*)d_in[0];
    const float* accs = (const float*)d_in[1];
    const int n = in_sizes[0];   // 16,777,216
    const int n4 = n / 4;

    // 2048 blocks = exactly 8/CU single-shot residency, 2 iters/block
    int nb = 2048;
    int ws_cap = (int)(ws_size / (NBINS * sizeof(float)));
    ws_cap &= ~3;
    if (nb > ws_cap) nb = ws_cap;
    if (nb < 4) nb = 4;

    float* partials = (float*)d_ws;

    ece_accum<<<nb, TPB, 0, stream>>>((const fvec4*)confs, (const fvec4*)accs,
                                      n4, partials, nb);
    ece_final<<<1, 512, 0, stream>>>(partials, (float*)d_out, 1.0f / (float)n, nb);
}

// Round 10
// 37.256 us; speedup vs baseline: 6.7710x; 1.0403x over previous
//
#include <hip/hip_runtime.h>
#include <hip/hip_bf16.h>

#define NBINS 20
#define TPB 256
#define K 4   // float4 loads per stream per thread per chunk

typedef float fvec4 __attribute__((ext_vector_type(4)));

// NT streaming loads (R9: -9%) + depth-2 software pipeline (prefetch next
// chunk's 8 dwordx4 before processing current) for continuous in-flight
// reads. Non-atomic LDS RMW s[bin][tid] (bank=tid%32, 2-way = free).
// bin = ceil((c-0.5)*40)-1 == searchsorted(side='left')-1 (absmax 0.0,
// rounds 1-9). launch_bounds(256,4): pipeline needs ~84 VGPR, no spill.
__global__ __launch_bounds__(TPB, 4) void ece_accum(
        const fvec4* __restrict__ confs,
        const fvec4* __restrict__ accs,
        int n4,                        // n/4
        float* __restrict__ partials,  // [NBINS][nb]
        int nb) {
    __shared__ float s[NBINS * TPB];
    const int t = threadIdx.x;
#pragma unroll
    for (int k = 0; k < NBINS; ++k) s[k * TPB + t] = 0.0f;
    __syncthreads();

    const int chunk = K * TPB;           // 1024 float4s per block-chunk
    const int nIter = n4 / chunk;        // 4096 for N=16.7M

    int it = blockIdx.x;
    fvec4 c[K], a[K];
    bool have = (it < nIter);
    if (have) {
        const int base = it * chunk + t;
#pragma unroll
        for (int k = 0; k < K; ++k) c[k] = __builtin_nontemporal_load(&confs[base + k * TPB]);
#pragma unroll
        for (int k = 0; k < K; ++k) a[k] = __builtin_nontemporal_load(&accs[base + k * TPB]);
    }

    while (have) {
        const int itn = it + gridDim.x;
        const bool hn = (itn < nIter);
        fvec4 nc[K], na[K];
        if (hn) {  // issue next chunk's loads BEFORE processing current
            const int nbase = itn * chunk + t;
#pragma unroll
            for (int k = 0; k < K; ++k) nc[k] = __builtin_nontemporal_load(&confs[nbase + k * TPB]);
#pragma unroll
            for (int k = 0; k < K; ++k) na[k] = __builtin_nontemporal_load(&accs[nbase + k * TPB]);
        }

#pragma unroll
        for (int k = 0; k < K; ++k) {
#pragma unroll
            for (int j = 0; j < 4; ++j) {
                float c1 = c[k][j];
                float a1 = a[k][j];
                float ft = __builtin_ceilf((c1 - 0.5f) * 40.0f);
                unsigned int bin = (unsigned int)((int)ft - 1);
                if (bin < (unsigned int)NBINS)
                    s[bin * TPB + t] += c1 - a1;
            }
        }

        it = itn;
        have = hn;
#pragma unroll
        for (int k = 0; k < K; ++k) { c[k] = nc[k]; a[k] = na[k]; }
    }

    // tail (n4 not multiple of chunk) — block 0
    if (blockIdx.x == 0) {
        for (int i = nIter * chunk + t; i < n4; i += TPB) {
            fvec4 c4 = confs[i];
            fvec4 a4 = accs[i];
#pragma unroll
            for (int j = 0; j < 4; ++j) {
                float c1 = c4[j];
                float a1 = a4[j];
                float ft = __builtin_ceilf((c1 - 0.5f) * 40.0f);
                unsigned int bin = (unsigned int)((int)ft - 1);
                if (bin < (unsigned int)NBINS)
                    s[bin * TPB + t] += c1 - a1;
            }
        }
    }
    __syncthreads();

    // block reduce, reusing s[]
    float v[NBINS];
#pragma unroll
    for (int b = 0; b < NBINS; ++b) v[b] = s[b * TPB + t];
#pragma unroll
    for (int b = 0; b < NBINS; ++b) {
#pragma unroll
        for (int m = 32; m >= 1; m >>= 1) v[b] += __shfl_xor(v[b], m, 64);
    }
    __syncthreads();
    const int wave = t >> 6, lane = t & 63;
    if (lane == 0) {
#pragma unroll
        for (int b = 0; b < NBINS; ++b) s[b * 4 + wave] = v[b];
    }
    __syncthreads();
    if (t < NBINS) {
        float sum = s[t * 4 + 0] + s[t * 4 + 1] + s[t * 4 + 2] + s[t * 4 + 3];
        partials[t * nb + blockIdx.x] = sum;
    }
}

// One block: reduce nb partials per bin, ece = sum_b |S_b| / N
__global__ __launch_bounds__(512) void ece_final(
        const float* __restrict__ partials,
        float* __restrict__ out,
        float inv_n, int nb) {
    float s[NBINS];
#pragma unroll
    for (int b = 0; b < NBINS; ++b) s[b] = 0.0f;

    const int tid = threadIdx.x;
    const int nb4 = nb >> 2;
#pragma unroll
    for (int b = 0; b < NBINS; ++b) {
        const fvec4* pb = (const fvec4*)(partials + b * nb);
        for (int k = tid; k < nb4; k += blockDim.x) {
            fvec4 v = pb[k];
            s[b] += (v[0] + v[1]) + (v[2] + v[3]);
        }
    }
#pragma unroll
    for (int b = 0; b < NBINS; ++b) {
#pragma unroll
        for (int m = 32; m >= 1; m >>= 1)
            s[b] += __shfl_xor(s[b], m, 64);
    }

    __shared__ float red[NBINS][8];
    const int wave = tid >> 6;
    const int lane = tid & 63;
    if (lane == 0) {
#pragma unroll
        for (int b = 0; b < NBINS; ++b) red[b][wave] = s[b];
    }
    __syncthreads();

    if (tid == 0) {
        float ece = 0.0f;
#pragma unroll
        for (int b = 0; b < NBINS; ++b) {
            float tt = 0.0f;
#pragma unroll
            for (int w = 0; w < 8; ++w) tt += red[b][w];
            ece += fabsf(tt);
        }
        out[0] = ece * inv_n;
    }
}

extern "C" void kernel_launch(void* const* d_in, const int* in_sizes, int n_in,
                              void* d_out, int out_size, void* d_ws, size_t ws_size,
                              hipStream_t stream) {
    const float* confs = (const float*)d_in[0];
    const float* accs = (const float*)d_in[1];
    const int n = in_sizes[0];   // 16,777,216
    const int n4 = n / 4;

    // 1024 blocks = 4/CU single-shot at (256,4); 4 pipelined iters/block
    int nb = 1024;
    int ws_cap = (int)(ws_size / (NBINS * sizeof(float)));
    ws_cap &= ~3;
    if (nb > ws_cap) nb = ws_cap;
    if (nb < 4) nb = 4;

    float* partials = (float*)d_ws;

    ece_accum<<<nb, TPB, 0, stream>>>((const fvec4*)confs, (const fvec4*)accs,
                                      n4, partials, nb);
    ece_final<<<1, 512, 0, stream>>>(partials, (float*)d_out, 1.0f / (float)n, nb);
}